// Round 20
// baseline (138.506 us; speedup 1.0000x reference)
//
#include <hip/hip_runtime.h>

#define NN   8192
#define DD   128
#define KM1  7
#define TPB  256
#define NBLK 512      // 16-col weight blocks per row

#define O0_END   57344
#define O1_END   7397376
#define O2_END   14737408
#define O3_END   22077440
#define TOTAL    23126016
#define NKEY     57344

typedef __attribute__((ext_vector_type(8))) short bf16x8;
typedef __attribute__((ext_vector_type(4))) float f32x4;

__device__ __forceinline__ unsigned mix32(unsigned h) {
  h ^= h >> 16; h *= 0x85ebca6bu; h ^= h >> 13; h *= 0xc2b2ae35u; h ^= h >> 16;
  return h;
}

// Weight of pair given dot (bf16 inputs). Same formula in both passes.
__device__ __forceinline__ float wfun(float dot, int col, int rowblk) {
  float d2m = fmaxf(fmaf(-2.f, dot, 2.f), 0.25f);      // clamped dist^2
  bool vb = ((col >> 3) != rowblk) && (d2m < 1.96f);   // block mask + dist<1.4
  float lgd = __log2f(d2m);
  float om  = fmaf(-0.25f, d2m, 1.f);
  float lgo = __log2f(om);
  float lgw = fmaf(-62.5f, lgo, fmaf(-63.f, lgd, -63.f));  // log2 w
  float w   = __builtin_amdgcn_exp2f(lgw);             // w in [8e-20, 5e20]
  return vb ? w : 0.f;
}

__device__ __forceinline__ float wave_incl_scan(float v, int lane) {
#pragma unroll
  for (int off = 1; off < 64; off <<= 1) {
    float t = __shfl_up(v, off);
    if (lane >= off) v += t;
  }
  return v;
}

// fp32 -> bf16 (RNE), 4 elems/thread
__global__ __launch_bounds__(256) void to_bf16(const float4* __restrict__ x4,
                                               ushort4* __restrict__ xb4) {
  const int i = blockIdx.x * 256 + threadIdx.x;
  float4 v = x4[i];
  ushort4 o;
  unsigned u;
  u = __float_as_uint(v.x); o.x = (unsigned short)((u + 0x7FFFu + ((u >> 16) & 1u)) >> 16);
  u = __float_as_uint(v.y); o.y = (unsigned short)((u + 0x7FFFu + ((u >> 16) & 1u)) >> 16);
  u = __float_as_uint(v.z); o.z = (unsigned short)((u + 0x7FFFu + ((u >> 16) & 1u)) >> 16);
  u = __float_as_uint(v.w); o.w = (unsigned short)((u + 0x7FFFu + ((u >> 16) & 1u)) >> 16);
  xb4[i] = o;
}

// Pass A (swapped operands, 64 rows/wave): wave = 64 rows x 128 cols (4 tiles).
// grid = 32 row-groups x 64 col-chunks = 2048 blocks -> 8 blocks/CU offered.
// Identical codegen config to R17 (launch_bounds(256,2), unroll 1, VGPR ~84).
__global__ __launch_bounds__(TPB, 2) void pass_a(const unsigned short* __restrict__ xb,
                                                 float* __restrict__ bs) {
  const int tid  = threadIdx.x;
  const int lane = tid & 63;
  const int wid  = tid >> 6;
  const int l15  = lane & 15;
  const int g    = lane >> 4;
  const int i0   = ((int)(blockIdx.x >> 6)) * 256 + wid * 64;  // wave's 64 rows
  const int oc   = (int)(blockIdx.x & 63);
  const int c0   = oc * 128;
  const int koff = g * 8;

  // row fragments (B operand, n = row): 4 groups of 16 rows, loaded once
  bf16x8 rw[4][4];
#pragma unroll
  for (int rg = 0; rg < 4; ++rg) {
    const unsigned short* rp = xb + (size_t)(i0 + rg * 16 + l15) * DD + koff;
#pragma unroll
    for (int kk = 0; kk < 4; ++kk)
      rw[rg][kk] = *reinterpret_cast<const bf16x8*>(rp + kk * 32);
  }

  float bsl[8];      // this lane's row (i0+lane): 8 block sums, static-indexed
#pragma unroll
  for (int j = 0; j < 8; ++j) bsl[j] = 0.f;

#pragma unroll 1
  for (int t = 0; t < 4; ++t) {           // 32-col tiles = 2 x 16-col blocks
    const int ct = c0 + t * 32;
    // col fragments (A operand, m = col): lane l15 -> col ct+mf*16+l15
    bf16x8 cf[2][4];
#pragma unroll
    for (int mf = 0; mf < 2; ++mf) {
      const unsigned short* cp = xb + (size_t)(ct + mf * 16 + l15) * DD + koff;
#pragma unroll
      for (int kk = 0; kk < 4; ++kk)
        cf[mf][kk] = *reinterpret_cast<const bf16x8*>(cp + kk * 32);
    }

    f32x4 acc[2][4];
#pragma unroll
    for (int mf = 0; mf < 2; ++mf)
#pragma unroll
      for (int rg = 0; rg < 4; ++rg) acc[mf][rg] = (f32x4){0.f, 0.f, 0.f, 0.f};

#pragma unroll
    for (int mf = 0; mf < 2; ++mf)
#pragma unroll
      for (int rg = 0; rg < 4; ++rg)
#pragma unroll
        for (int kk = 0; kk < 4; ++kk)
          acc[mf][rg] = __builtin_amdgcn_mfma_f32_16x16x32_bf16(cf[mf][kk], rw[rg][kk],
                                                                acc[mf][rg], 0, 0, 0);

    // D layout [m89]: n = l15 -> ROW (group rg); m = g*4+reg -> COL
#pragma unroll
    for (int mf = 0; mf < 2; ++mf) {
      float s[4];
#pragma unroll
      for (int rg = 0; rg < 4; ++rg) {
        const int rowblk = (i0 + rg * 16 + l15) >> 3;
        float sv = 0.f;
#pragma unroll
        for (int r = 0; r < 4; ++r) {
          const int col = ct + mf * 16 + g * 4 + r;
          sv += wfun(acc[mf][rg][r], col, rowblk);
        }
        sv += __shfl_xor(sv, 16);
        sv += __shfl_xor(sv, 32);          // sum over g -> 16-col block sum
        s[rg] = sv;
      }
      // keep the rg == g slice: lane now owns row i0+lane
      float v = (g == 0) ? s[0] : (g == 1) ? s[1] : (g == 2) ? s[2] : s[3];
      bsl[2 * t + mf] = v;
    }
  }

  // coalesced write: lane's row chunk = 8 consecutive floats (32 B)
  float* dst = bs + (size_t)(i0 + lane) * NBLK + oc * 8;
  f32x4 o0 = {bsl[0], bsl[1], bsl[2], bsl[3]};
  f32x4 o1 = {bsl[4], bsl[5], bsl[6], bsl[7]};
  *reinterpret_cast<f32x4*>(dst)     = o0;
  *reinterpret_cast<f32x4*>(dst + 4) = o1;
}

// Pass B: one wave per draw. Two-level inverse-CDF: 512 block sums -> 16-col
// block -> fp32 recompute of the 16 weights (4 lanes/col x 32 dims).
__global__ __launch_bounds__(TPB) void pass_b(const unsigned short* __restrict__ xb,
                                              const float* __restrict__ bs,
                                              unsigned* __restrict__ nidx) {
  const int lane = threadIdx.x & 63;
  const int wid  = threadIdx.x >> 6;
  const int draw = (int)blockIdx.x * 4 + wid;   // 57344 draws
  const int row  = draw / KM1;

  // ---- stage 1: scan the row's 512 block sums (8 per lane)
  const float* bsr = bs + (size_t)row * NBLK;
  float4 v0 = *reinterpret_cast<const float4*>(bsr + lane * 8);
  float4 v1 = *reinterpret_cast<const float4*>(bsr + lane * 8 + 4);
  float s8 = ((v0.x + v0.y) + (v0.z + v0.w)) + ((v1.x + v1.y) + (v1.z + v1.w));
  float pre = wave_incl_scan(s8, lane);
  float W = __shfl(pre, 63);

  unsigned h = mix32((unsigned)draw * 2654435761u + 0x12345u);
  float u = ((float)(h >> 9) + 0.5f) * (1.0f / 8388608.0f);   // (0,1)

  if (!(W > 0.f)) {  // degenerate row -> uniform over all n
    if (lane == 0) nidx[draw] = mix32((unsigned)draw * 0x68bc21ebu + 77u) & (NN - 1);
    return;
  }
  float target = u * W;

  unsigned long long ball = __ballot(pre >= target);
  int Lc = ball ? ((int)__ffsll(ball) - 1) : 63;
  float exL = __shfl(pre - s8, Lc);
  float a0 = __shfl(v0.x, Lc), a1 = __shfl(v0.y, Lc), a2 = __shfl(v0.z, Lc),
        a3 = __shfl(v0.w, Lc), a4 = __shfl(v1.x, Lc), a5 = __shfl(v1.y, Lc),
        a6 = __shfl(v1.z, Lc), a7 = __shfl(v1.w, Lc);
  // uniform scalar selection among the 8 (static indexing only)
  int k = -1; float res = 0.f, bsb = 0.f, c = exL;
#define PICK(j, aj) { float cn = c + (aj); if (k < 0 && cn >= target) { k = j; res = target - c; bsb = (aj); } c = cn; }
  PICK(0, a0) PICK(1, a1) PICK(2, a2) PICK(3, a3)
  PICK(4, a4) PICK(5, a5) PICK(6, a6) PICK(7, a7)
#undef PICK
#define LASTP(j, aj) { if (k < 0 && (aj) > 0.f) { k = j; res = (aj); bsb = (aj); } }
  LASTP(7, a7) LASTP(6, a6) LASTP(5, a5) LASTP(4, a4)
  LASTP(3, a3) LASTP(2, a2) LASTP(1, a1) LASTP(0, a0)
#undef LASTP
  if (k < 0) {  // pathological: chosen lane empty -> uniform fallback
    if (lane == 0) nidx[draw] = mix32((unsigned)draw * 0x68bc21ebu + 77u) & (NN - 1);
    return;
  }
  const int blk = Lc * 8 + k;
  const int cb  = blk * 16;

  // ---- stage 2: recompute the 16 weights in fp32 (4 lanes/col x 32 dims)
  const int c_local = lane >> 2;
  const int part    = lane & 3;
  const int col     = cb + c_local;
  const unsigned short* cp = xb + (size_t)col * DD + part * 32;
  const unsigned short* ap = xb + (size_t)row * DD + part * 32;
  float dot = 0.f;
#pragma unroll
  for (int vv = 0; vv < 4; ++vv) {
    bf16x8 cv = *reinterpret_cast<const bf16x8*>(cp + vv * 8);
    bf16x8 av = *reinterpret_cast<const bf16x8*>(ap + vv * 8);
#pragma unroll
    for (int j = 0; j < 8; ++j) {
      float cf = __uint_as_float(((unsigned)(unsigned short)cv[j]) << 16);
      float af = __uint_as_float(((unsigned)(unsigned short)av[j]) << 16);
      dot = fmaf(cf, af, dot);
    }
  }
  dot += __shfl_xor(dot, 1);
  dot += __shfl_xor(dot, 2);
  float w = wfun(dot, col, row >> 3);
  float v = (part == 0) ? w : 0.f;
  float pre2 = wave_incl_scan(v, lane);
  float SW = __shfl(pre2, 63);
  unsigned result;
  if (SW > 0.f) {
    float t2 = (res / bsb) * SW;                 // renormalized residual
    unsigned long long m = __ballot((v > 0.f) && (pre2 >= t2));
    if (m) result = (unsigned)(cb + (((int)__ffsll(m) - 1) >> 2));
    else {
      unsigned long long m2 = __ballot(v > 0.f); // rounding overrun -> clamp
      result = (unsigned)(cb + ((63 - (int)__clzll(m2)) >> 2));
    }
  } else {
    result = mix32((unsigned)draw * 0x68bc21ebu + 77u) & (NN - 1);
  }
  if (lane == 0) nidx[draw] = result;
}

// All five output chunks, float4-vectorized, nontemporal stores (R17 version).
__global__ __launch_bounds__(256) void write_outputs(const float* __restrict__ x,
                                                     const unsigned* __restrict__ nidx,
                                                     float* __restrict__ out) {
  const int qq = blockIdx.x * 256 + threadIdx.x;
  if (qq >= TOTAL / 4) return;
  const int e = qq * 4;
  float4 v;
  if (e < O0_END) {
    v.x = (float)((e    ) / KM1);
    v.y = (float)((e + 1) / KM1);
    v.z = (float)((e + 2) / KM1);
    v.w = (float)((e + 3) / KM1);                        // a_idx
  } else if (e < O1_END) {
    int t = e - O0_END; int sidx = t >> 7; int d = t & 127;
    v = *reinterpret_cast<const float4*>(x + (size_t)(sidx / KM1) * DD + d);   // x[a_idx]
  } else if (e < O2_END) {
    int t = e - O1_END; int sidx = t >> 7; int d = t & 127;
    int i = sidx / KM1; int j = sidx - i * KM1; int m = i & 7;
    int p = (i >> 3) * 8 + j + (j >= m ? 1 : 0);         // block members, skip self
    v = *reinterpret_cast<const float4*>(x + (size_t)p * DD + d);              // x[p_idx]
  } else if (e < O3_END) {
    int t = e - O2_END; int sidx = t >> 7; int d = t & 127;
    int nix = (int)nidx[sidx];
    v = *reinterpret_cast<const float4*>(x + (size_t)nix * DD + d);            // x[n_idx]
  } else {
    v = *reinterpret_cast<const float4*>(x + (e - O3_END));                    // x
  }
  f32x4 nv = {v.x, v.y, v.z, v.w};
  __builtin_nontemporal_store(nv, reinterpret_cast<f32x4*>(out + e));
}

extern "C" void kernel_launch(void* const* d_in, const int* in_sizes, int n_in,
                              void* d_out, int out_size, void* d_ws, size_t ws_size,
                              hipStream_t stream) {
  const float* x = (const float*)d_in[0];
  float* out = (float*)d_out;

  float* bs = (float*)d_ws;                                           // 8192*512 f32 = 16MB
  unsigned* nidx = (unsigned*)((char*)d_ws + (size_t)NN * NBLK * 4);  // 57344 u32
  unsigned short* xb = (unsigned short*)((char*)nidx + NKEY * 4);     // 2MB bf16

  hipLaunchKernelGGL(to_bf16, dim3(NN * DD / 4 / 256), dim3(256), 0, stream,
                     (const float4*)x, (ushort4*)xb);
  hipLaunchKernelGGL(pass_a, dim3(2048), dim3(TPB), 0, stream, xb, bs);
  hipLaunchKernelGGL(pass_b, dim3(NKEY / 4), dim3(TPB), 0, stream, xb, bs, nidx);
  hipLaunchKernelGGL(write_outputs, dim3(TOTAL / 4 / 256), dim3(256), 0, stream,
                     x, nidx, out);
}

// Round 21
// 136.445 us; speedup vs baseline: 1.0151x; 1.0151x over previous
//
#include <hip/hip_runtime.h>

#define NN   8192
#define DD   128
#define KM1  7
#define TPB  256
#define NBLK 512      // 16-col weight blocks per row

#define O0_END   57344
#define O1_END   7397376
#define O2_END   14737408
#define O3_END   22077440
#define TOTAL    23126016
#define NKEY     57344

typedef __attribute__((ext_vector_type(8))) short bf16x8;
typedef __attribute__((ext_vector_type(4))) float f32x4;

__device__ __forceinline__ unsigned mix32(unsigned h) {
  h ^= h >> 16; h *= 0x85ebca6bu; h ^= h >> 13; h *= 0xc2b2ae35u; h ^= h >> 16;
  return h;
}

// Weight of pair given dot (bf16 inputs). Same formula in both passes.
__device__ __forceinline__ float wfun(float dot, int col, int rowblk) {
  float d2m = fmaxf(fmaf(-2.f, dot, 2.f), 0.25f);      // clamped dist^2
  bool vb = ((col >> 3) != rowblk) && (d2m < 1.96f);   // block mask + dist<1.4
  float lgd = __log2f(d2m);
  float om  = fmaf(-0.25f, d2m, 1.f);
  float lgo = __log2f(om);
  float lgw = fmaf(-62.5f, lgo, fmaf(-63.f, lgd, -63.f));  // log2 w
  float w   = __builtin_amdgcn_exp2f(lgw);             // w in [8e-20, 5e20]
  return vb ? w : 0.f;
}

__device__ __forceinline__ float wave_incl_scan(float v, int lane) {
#pragma unroll
  for (int off = 1; off < 64; off <<= 1) {
    float t = __shfl_up(v, off);
    if (lane >= off) v += t;
  }
  return v;
}

// fp32 -> bf16 (RNE), 4 elems/thread
__global__ __launch_bounds__(256) void to_bf16(const float4* __restrict__ x4,
                                               ushort4* __restrict__ xb4) {
  const int i = blockIdx.x * 256 + threadIdx.x;
  float4 v = x4[i];
  ushort4 o;
  unsigned u;
  u = __float_as_uint(v.x); o.x = (unsigned short)((u + 0x7FFFu + ((u >> 16) & 1u)) >> 16);
  u = __float_as_uint(v.y); o.y = (unsigned short)((u + 0x7FFFu + ((u >> 16) & 1u)) >> 16);
  u = __float_as_uint(v.z); o.z = (unsigned short)((u + 0x7FFFu + ((u >> 16) & 1u)) >> 16);
  u = __float_as_uint(v.w); o.w = (unsigned short)((u + 0x7FFFu + ((u >> 16) & 1u)) >> 16);
  xb4[i] = o;
}

// ---- pass_a tile macros: named static-indexed buffers, no lambdas/arrays-as-params
#define LOAD_CF(C0, C1, tt)                                                 \
  {                                                                         \
    const int ct_ = c0 + (tt) * 32;                                         \
    const unsigned short* p0_ = xb + (size_t)(ct_ + l15) * DD + koff;       \
    const unsigned short* p1_ = xb + (size_t)(ct_ + 16 + l15) * DD + koff;  \
    C0[0] = *reinterpret_cast<const bf16x8*>(p0_);                          \
    C0[1] = *reinterpret_cast<const bf16x8*>(p0_ + 32);                     \
    C0[2] = *reinterpret_cast<const bf16x8*>(p0_ + 64);                     \
    C0[3] = *reinterpret_cast<const bf16x8*>(p0_ + 96);                     \
    C1[0] = *reinterpret_cast<const bf16x8*>(p1_);                          \
    C1[1] = *reinterpret_cast<const bf16x8*>(p1_ + 32);                     \
    C1[2] = *reinterpret_cast<const bf16x8*>(p1_ + 64);                     \
    C1[3] = *reinterpret_cast<const bf16x8*>(p1_ + 96);                     \
  }

#define COMP_TILE(C0, C1, tt)                                               \
  {                                                                         \
    const int ct_ = c0 + (tt) * 32;                                         \
    f32x4 acc_[2][4];                                                       \
    _Pragma("unroll") for (int mf = 0; mf < 2; ++mf)                        \
      _Pragma("unroll") for (int rg = 0; rg < 4; ++rg)                      \
        acc_[mf][rg] = (f32x4){0.f, 0.f, 0.f, 0.f};                         \
    _Pragma("unroll") for (int rg = 0; rg < 4; ++rg)                        \
      _Pragma("unroll") for (int kk = 0; kk < 4; ++kk) {                    \
        acc_[0][rg] = __builtin_amdgcn_mfma_f32_16x16x32_bf16(              \
            C0[kk], rw[rg][kk], acc_[0][rg], 0, 0, 0);                      \
        acc_[1][rg] = __builtin_amdgcn_mfma_f32_16x16x32_bf16(              \
            C1[kk], rw[rg][kk], acc_[1][rg], 0, 0, 0);                      \
      }                                                                     \
    _Pragma("unroll") for (int mf = 0; mf < 2; ++mf) {                      \
      float s_[4];                                                          \
      _Pragma("unroll") for (int rg = 0; rg < 4; ++rg) {                    \
        const int rowblk_ = (i0 + rg * 16 + l15) >> 3;                      \
        float sv_ = 0.f;                                                    \
        _Pragma("unroll") for (int r = 0; r < 4; ++r) {                     \
          const int col_ = ct_ + mf * 16 + g * 4 + r;                       \
          sv_ += wfun(acc_[mf][rg][r], col_, rowblk_);                      \
        }                                                                   \
        sv_ += __shfl_xor(sv_, 16);                                         \
        sv_ += __shfl_xor(sv_, 32);                                         \
        s_[rg] = sv_;                                                       \
      }                                                                     \
      float v_ = (g == 0) ? s_[0] : (g == 1) ? s_[1] : (g == 2) ? s_[2] : s_[3]; \
      bsl[2 * (tt) + mf] = v_;                                              \
    }                                                                       \
  }

// Pass A (swapped operands, 64 rows/wave): wave = 64 rows x 256 cols (8 tiles),
// grid = 32 row-groups x 32 col-chunks = 1024 blocks (R17 shape). Col-fragment
// loads double-buffered (cA/cB) so tile t+1's L2 gather latency hides under
// tile t's MFMA+epilogue.
__global__ __launch_bounds__(TPB, 2) void pass_a(const unsigned short* __restrict__ xb,
                                                 float* __restrict__ bs) {
  const int tid  = threadIdx.x;
  const int lane = tid & 63;
  const int wid  = tid >> 6;
  const int l15  = lane & 15;
  const int g    = lane >> 4;
  const int i0   = ((int)(blockIdx.x >> 5)) * 256 + wid * 64;  // wave's 64 rows
  const int oc   = (int)(blockIdx.x & 31);
  const int c0   = oc * 256;
  const int koff = g * 8;

  // row fragments (B operand, n = row): 4 groups of 16 rows, loaded once
  bf16x8 rw[4][4];
#pragma unroll
  for (int rg = 0; rg < 4; ++rg) {
    const unsigned short* rp = xb + (size_t)(i0 + rg * 16 + l15) * DD + koff;
#pragma unroll
    for (int kk = 0; kk < 4; ++kk)
      rw[rg][kk] = *reinterpret_cast<const bf16x8*>(rp + kk * 32);
  }

  float bsl[16];     // this lane's row (i0+lane): 16 block sums, static-indexed
#pragma unroll
  for (int j = 0; j < 16; ++j) bsl[j] = 0.f;

  bf16x8 cA0[4], cA1[4], cB0[4], cB1[4];
  LOAD_CF(cA0, cA1, 0)
#pragma unroll 1
  for (int t = 0; t < 8; t += 2) {
    LOAD_CF(cB0, cB1, t + 1)          // prefetch t+1 while computing t
    COMP_TILE(cA0, cA1, t)
    if (t + 2 < 8) LOAD_CF(cA0, cA1, t + 2)   // prefetch t+2 while computing t+1
    COMP_TILE(cB0, cB1, t + 1)
  }

  // coalesced write: lane's row chunk = 16 consecutive floats (one 64 B line)
  float* dst = bs + (size_t)(i0 + lane) * NBLK + oc * 16;
#pragma unroll
  for (int k4 = 0; k4 < 4; ++k4) {
    f32x4 o = {bsl[4 * k4], bsl[4 * k4 + 1], bsl[4 * k4 + 2], bsl[4 * k4 + 3]};
    *reinterpret_cast<f32x4*>(dst + 4 * k4) = o;
  }
}

// Pass B: one wave per draw. Two-level inverse-CDF: 512 block sums -> 16-col
// block -> fp32 recompute of the 16 weights (4 lanes/col x 32 dims).
__global__ __launch_bounds__(TPB) void pass_b(const unsigned short* __restrict__ xb,
                                              const float* __restrict__ bs,
                                              unsigned* __restrict__ nidx) {
  const int lane = threadIdx.x & 63;
  const int wid  = threadIdx.x >> 6;
  const int draw = (int)blockIdx.x * 4 + wid;   // 57344 draws
  const int row  = draw / KM1;

  // ---- stage 1: scan the row's 512 block sums (8 per lane)
  const float* bsr = bs + (size_t)row * NBLK;
  float4 v0 = *reinterpret_cast<const float4*>(bsr + lane * 8);
  float4 v1 = *reinterpret_cast<const float4*>(bsr + lane * 8 + 4);
  float s8 = ((v0.x + v0.y) + (v0.z + v0.w)) + ((v1.x + v1.y) + (v1.z + v1.w));
  float pre = wave_incl_scan(s8, lane);
  float W = __shfl(pre, 63);

  unsigned h = mix32((unsigned)draw * 2654435761u + 0x12345u);
  float u = ((float)(h >> 9) + 0.5f) * (1.0f / 8388608.0f);   // (0,1)

  if (!(W > 0.f)) {  // degenerate row -> uniform over all n
    if (lane == 0) nidx[draw] = mix32((unsigned)draw * 0x68bc21ebu + 77u) & (NN - 1);
    return;
  }
  float target = u * W;

  unsigned long long ball = __ballot(pre >= target);
  int Lc = ball ? ((int)__ffsll(ball) - 1) : 63;
  float exL = __shfl(pre - s8, Lc);
  float a0 = __shfl(v0.x, Lc), a1 = __shfl(v0.y, Lc), a2 = __shfl(v0.z, Lc),
        a3 = __shfl(v0.w, Lc), a4 = __shfl(v1.x, Lc), a5 = __shfl(v1.y, Lc),
        a6 = __shfl(v1.z, Lc), a7 = __shfl(v1.w, Lc);
  // uniform scalar selection among the 8 (static indexing only)
  int k = -1; float res = 0.f, bsb = 0.f, c = exL;
#define PICK(j, aj) { float cn = c + (aj); if (k < 0 && cn >= target) { k = j; res = target - c; bsb = (aj); } c = cn; }
  PICK(0, a0) PICK(1, a1) PICK(2, a2) PICK(3, a3)
  PICK(4, a4) PICK(5, a5) PICK(6, a6) PICK(7, a7)
#undef PICK
#define LASTP(j, aj) { if (k < 0 && (aj) > 0.f) { k = j; res = (aj); bsb = (aj); } }
  LASTP(7, a7) LASTP(6, a6) LASTP(5, a5) LASTP(4, a4)
  LASTP(3, a3) LASTP(2, a2) LASTP(1, a1) LASTP(0, a0)
#undef LASTP
  if (k < 0) {  // pathological: chosen lane empty -> uniform fallback
    if (lane == 0) nidx[draw] = mix32((unsigned)draw * 0x68bc21ebu + 77u) & (NN - 1);
    return;
  }
  const int blk = Lc * 8 + k;
  const int cb  = blk * 16;

  // ---- stage 2: recompute the 16 weights in fp32 (4 lanes/col x 32 dims)
  const int c_local = lane >> 2;
  const int part    = lane & 3;
  const int col     = cb + c_local;
  const unsigned short* cp = xb + (size_t)col * DD + part * 32;
  const unsigned short* ap = xb + (size_t)row * DD + part * 32;
  float dot = 0.f;
#pragma unroll
  for (int vv = 0; vv < 4; ++vv) {
    bf16x8 cv = *reinterpret_cast<const bf16x8*>(cp + vv * 8);
    bf16x8 av = *reinterpret_cast<const bf16x8*>(ap + vv * 8);
#pragma unroll
    for (int j = 0; j < 8; ++j) {
      float cf = __uint_as_float(((unsigned)(unsigned short)cv[j]) << 16);
      float af = __uint_as_float(((unsigned)(unsigned short)av[j]) << 16);
      dot = fmaf(cf, af, dot);
    }
  }
  dot += __shfl_xor(dot, 1);
  dot += __shfl_xor(dot, 2);
  float w = wfun(dot, col, row >> 3);
  float v = (part == 0) ? w : 0.f;
  float pre2 = wave_incl_scan(v, lane);
  float SW = __shfl(pre2, 63);
  unsigned result;
  if (SW > 0.f) {
    float t2 = (res / bsb) * SW;                 // renormalized residual
    unsigned long long m = __ballot((v > 0.f) && (pre2 >= t2));
    if (m) result = (unsigned)(cb + (((int)__ffsll(m) - 1) >> 2));
    else {
      unsigned long long m2 = __ballot(v > 0.f); // rounding overrun -> clamp
      result = (unsigned)(cb + ((63 - (int)__clzll(m2)) >> 2));
    }
  } else {
    result = mix32((unsigned)draw * 0x68bc21ebu + 77u) & (NN - 1);
  }
  if (lane == 0) nidx[draw] = result;
}

// All five output chunks, float4-vectorized, nontemporal stores (R17 version).
__global__ __launch_bounds__(256) void write_outputs(const float* __restrict__ x,
                                                     const unsigned* __restrict__ nidx,
                                                     float* __restrict__ out) {
  const int qq = blockIdx.x * 256 + threadIdx.x;
  if (qq >= TOTAL / 4) return;
  const int e = qq * 4;
  float4 v;
  if (e < O0_END) {
    v.x = (float)((e    ) / KM1);
    v.y = (float)((e + 1) / KM1);
    v.z = (float)((e + 2) / KM1);
    v.w = (float)((e + 3) / KM1);                        // a_idx
  } else if (e < O1_END) {
    int t = e - O0_END; int sidx = t >> 7; int d = t & 127;
    v = *reinterpret_cast<const float4*>(x + (size_t)(sidx / KM1) * DD + d);   // x[a_idx]
  } else if (e < O2_END) {
    int t = e - O1_END; int sidx = t >> 7; int d = t & 127;
    int i = sidx / KM1; int j = sidx - i * KM1; int m = i & 7;
    int p = (i >> 3) * 8 + j + (j >= m ? 1 : 0);         // block members, skip self
    v = *reinterpret_cast<const float4*>(x + (size_t)p * DD + d);              // x[p_idx]
  } else if (e < O3_END) {
    int t = e - O2_END; int sidx = t >> 7; int d = t & 127;
    int nix = (int)nidx[sidx];
    v = *reinterpret_cast<const float4*>(x + (size_t)nix * DD + d);            // x[n_idx]
  } else {
    v = *reinterpret_cast<const float4*>(x + (e - O3_END));                    // x
  }
  f32x4 nv = {v.x, v.y, v.z, v.w};
  __builtin_nontemporal_store(nv, reinterpret_cast<f32x4*>(out + e));
}

extern "C" void kernel_launch(void* const* d_in, const int* in_sizes, int n_in,
                              void* d_out, int out_size, void* d_ws, size_t ws_size,
                              hipStream_t stream) {
  const float* x = (const float*)d_in[0];
  float* out = (float*)d_out;

  float* bs = (float*)d_ws;                                           // 8192*512 f32 = 16MB
  unsigned* nidx = (unsigned*)((char*)d_ws + (size_t)NN * NBLK * 4);  // 57344 u32
  unsigned short* xb = (unsigned short*)((char*)nidx + NKEY * 4);     // 2MB bf16

  hipLaunchKernelGGL(to_bf16, dim3(NN * DD / 4 / 256), dim3(256), 0, stream,
                     (const float4*)x, (ushort4*)xb);
  hipLaunchKernelGGL(pass_a, dim3(1024), dim3(TPB), 0, stream, xb, bs);
  hipLaunchKernelGGL(pass_b, dim3(NKEY / 4), dim3(TPB), 0, stream, xb, bs, nidx);
  hipLaunchKernelGGL(write_outputs, dim3(TOTAL / 4 / 256), dim3(256), 0, stream,
                     x, nidx, out);
}

// Round 22
// 127.463 us; speedup vs baseline: 1.0866x; 1.0705x over previous
//
#include <hip/hip_runtime.h>

#define NN   8192
#define DD   128
#define KM1  7
#define TPB  256
#define NBLK 512      // 16-col weight blocks per row

#define O0_END   57344
#define O1_END   7397376
#define O2_END   14737408
#define O3_END   22077440
#define TOTAL    23126016
#define NKEY     57344

typedef __attribute__((ext_vector_type(8))) short bf16x8;
typedef __attribute__((ext_vector_type(4))) float f32x4;

__device__ __forceinline__ unsigned mix32(unsigned h) {
  h ^= h >> 16; h *= 0x85ebca6bu; h ^= h >> 13; h *= 0xc2b2ae35u; h ^= h >> 16;
  return h;
}

// Weight of pair given dot (bf16 inputs). Same formula in both passes.
__device__ __forceinline__ float wfun(float dot, int col, int rowblk) {
  float d2m = fmaxf(fmaf(-2.f, dot, 2.f), 0.25f);      // clamped dist^2
  bool vb = ((col >> 3) != rowblk) && (d2m < 1.96f);   // block mask + dist<1.4
  float lgd = __log2f(d2m);
  float om  = fmaf(-0.25f, d2m, 1.f);
  float lgo = __log2f(om);
  float lgw = fmaf(-62.5f, lgo, fmaf(-63.f, lgd, -63.f));  // log2 w
  float w   = __builtin_amdgcn_exp2f(lgw);             // w in [8e-20, 5e20]
  return vb ? w : 0.f;
}

__device__ __forceinline__ float wave_incl_scan(float v, int lane) {
#pragma unroll
  for (int off = 1; off < 64; off <<= 1) {
    float t = __shfl_up(v, off);
    if (lane >= off) v += t;
  }
  return v;
}

// fp32 -> bf16 (RNE) into FRAGMENT-SWIZZLED layout xbf:
// chunk c = R*256 + kk*64 + g*16 + l15 holds x[16R+l15][kk*32+g*8 .. +8) (bf16x8)
// -> MFMA fragment loads become lane-consecutive (fully coalesced 1 KB/wave).
__global__ __launch_bounds__(256) void to_bf16(const float* __restrict__ x,
                                               unsigned short* __restrict__ xbf) {
  const int c = blockIdx.x * 256 + threadIdx.x;   // 131072 chunks
  const int l15 = c & 15, g = (c >> 4) & 3, kk = (c >> 6) & 3, R = c >> 8;
  const int row = R * 16 + l15;
  const int j0  = kk * 32 + g * 8;
  const float* src = x + (size_t)row * DD + j0;
  float4 a = *reinterpret_cast<const float4*>(src);
  float4 b = *reinterpret_cast<const float4*>(src + 4);
  unsigned short o[8];
  unsigned u;
  u = __float_as_uint(a.x); o[0] = (unsigned short)((u + 0x7FFFu + ((u >> 16) & 1u)) >> 16);
  u = __float_as_uint(a.y); o[1] = (unsigned short)((u + 0x7FFFu + ((u >> 16) & 1u)) >> 16);
  u = __float_as_uint(a.z); o[2] = (unsigned short)((u + 0x7FFFu + ((u >> 16) & 1u)) >> 16);
  u = __float_as_uint(a.w); o[3] = (unsigned short)((u + 0x7FFFu + ((u >> 16) & 1u)) >> 16);
  u = __float_as_uint(b.x); o[4] = (unsigned short)((u + 0x7FFFu + ((u >> 16) & 1u)) >> 16);
  u = __float_as_uint(b.y); o[5] = (unsigned short)((u + 0x7FFFu + ((u >> 16) & 1u)) >> 16);
  u = __float_as_uint(b.z); o[6] = (unsigned short)((u + 0x7FFFu + ((u >> 16) & 1u)) >> 16);
  u = __float_as_uint(b.w); o[7] = (unsigned short)((u + 0x7FFFu + ((u >> 16) & 1u)) >> 16);
  bf16x8 pk;
#pragma unroll
  for (int j = 0; j < 8; ++j) pk[j] = (short)o[j];
  *reinterpret_cast<bf16x8*>(xbf + (size_t)c * 8) = pk;
}

// Pass A (swapped operands, 64 rows/wave): wave = 64 rows x 256 cols (8 tiles),
// grid = 32 row-groups x 32 col-chunks = 1024 blocks (R17 config). All fragment
// loads from xbf are lane-consecutive -> fully coalesced.
__global__ __launch_bounds__(TPB, 2) void pass_a(const unsigned short* __restrict__ xbf,
                                                 float* __restrict__ bs) {
  const int tid  = threadIdx.x;
  const int lane = tid & 63;
  const int wid  = tid >> 6;
  const int l15  = lane & 15;
  const int g    = lane >> 4;
  const int i0   = ((int)(blockIdx.x >> 5)) * 256 + wid * 64;  // wave's 64 rows
  const int oc   = (int)(blockIdx.x & 31);
  const int c0   = oc * 256;

  // row fragments: group (i0>>4)+rg, chunk base + kk*512 + lane*8 elements
  bf16x8 rw[4][4];
#pragma unroll
  for (int rg = 0; rg < 4; ++rg) {
    const unsigned short* rp = xbf + ((size_t)(i0 >> 4) + rg) * 2048 + lane * 8;
#pragma unroll
    for (int kk = 0; kk < 4; ++kk)
      rw[rg][kk] = *reinterpret_cast<const bf16x8*>(rp + kk * 512);
  }

  float bsl[16];     // this lane's row (i0+lane): 16 block sums, static-indexed
#pragma unroll
  for (int j = 0; j < 16; ++j) bsl[j] = 0.f;

#pragma unroll 1
  for (int t = 0; t < 8; ++t) {           // 32-col tiles = 2 x 16-col blocks
    const int ct = c0 + t * 32;
    bf16x8 cf[2][4];
#pragma unroll
    for (int mf = 0; mf < 2; ++mf) {
      const unsigned short* cp = xbf + ((size_t)(ct >> 4) + mf) * 2048 + lane * 8;
#pragma unroll
      for (int kk = 0; kk < 4; ++kk)
        cf[mf][kk] = *reinterpret_cast<const bf16x8*>(cp + kk * 512);
    }

    f32x4 acc[2][4];
#pragma unroll
    for (int mf = 0; mf < 2; ++mf)
#pragma unroll
      for (int rg = 0; rg < 4; ++rg) acc[mf][rg] = (f32x4){0.f, 0.f, 0.f, 0.f};

#pragma unroll
    for (int mf = 0; mf < 2; ++mf)
#pragma unroll
      for (int rg = 0; rg < 4; ++rg)
#pragma unroll
        for (int kk = 0; kk < 4; ++kk)
          acc[mf][rg] = __builtin_amdgcn_mfma_f32_16x16x32_bf16(cf[mf][kk], rw[rg][kk],
                                                                acc[mf][rg], 0, 0, 0);

    // D layout [m89]: n = l15 -> ROW (group rg); m = g*4+reg -> COL
#pragma unroll
    for (int mf = 0; mf < 2; ++mf) {
      float s[4];
#pragma unroll
      for (int rg = 0; rg < 4; ++rg) {
        const int rowblk = (i0 + rg * 16 + l15) >> 3;
        float sv = 0.f;
#pragma unroll
        for (int r = 0; r < 4; ++r) {
          const int col = ct + mf * 16 + g * 4 + r;
          sv += wfun(acc[mf][rg][r], col, rowblk);
        }
        sv += __shfl_xor(sv, 16);
        sv += __shfl_xor(sv, 32);          // sum over g -> 16-col block sum
        s[rg] = sv;
      }
      // keep the rg == g slice: lane now owns row i0+lane
      float v = (g == 0) ? s[0] : (g == 1) ? s[1] : (g == 2) ? s[2] : s[3];
      bsl[2 * t + mf] = v;
    }
  }

  // coalesced write: lane's row chunk = 16 consecutive floats (one 64 B line)
  float* dst = bs + (size_t)(i0 + lane) * NBLK + oc * 16;
#pragma unroll
  for (int k4 = 0; k4 < 4; ++k4) {
    f32x4 o = {bsl[4 * k4], bsl[4 * k4 + 1], bsl[4 * k4 + 2], bsl[4 * k4 + 3]};
    *reinterpret_cast<f32x4*>(dst + 4 * k4) = o;
  }
}

// Pass B: one wave per draw. Two-level inverse-CDF: 512 block sums -> 16-col
// block -> fp32 recompute of the 16 weights (4 lanes/col x 32 dims), reading
// the swizzled xbf layout.
__global__ __launch_bounds__(TPB) void pass_b(const unsigned short* __restrict__ xbf,
                                              const float* __restrict__ bs,
                                              unsigned* __restrict__ nidx) {
  const int lane = threadIdx.x & 63;
  const int wid  = threadIdx.x >> 6;
  const int draw = (int)blockIdx.x * 4 + wid;   // 57344 draws
  const int row  = draw / KM1;

  // ---- stage 1: scan the row's 512 block sums (8 per lane)
  const float* bsr = bs + (size_t)row * NBLK;
  float4 v0 = *reinterpret_cast<const float4*>(bsr + lane * 8);
  float4 v1 = *reinterpret_cast<const float4*>(bsr + lane * 8 + 4);
  float s8 = ((v0.x + v0.y) + (v0.z + v0.w)) + ((v1.x + v1.y) + (v1.z + v1.w));
  float pre = wave_incl_scan(s8, lane);
  float W = __shfl(pre, 63);

  unsigned h = mix32((unsigned)draw * 2654435761u + 0x12345u);
  float u = ((float)(h >> 9) + 0.5f) * (1.0f / 8388608.0f);   // (0,1)

  if (!(W > 0.f)) {  // degenerate row -> uniform over all n
    if (lane == 0) nidx[draw] = mix32((unsigned)draw * 0x68bc21ebu + 77u) & (NN - 1);
    return;
  }
  float target = u * W;

  unsigned long long ball = __ballot(pre >= target);
  int Lc = ball ? ((int)__ffsll(ball) - 1) : 63;
  float exL = __shfl(pre - s8, Lc);
  float a0 = __shfl(v0.x, Lc), a1 = __shfl(v0.y, Lc), a2 = __shfl(v0.z, Lc),
        a3 = __shfl(v0.w, Lc), a4 = __shfl(v1.x, Lc), a5 = __shfl(v1.y, Lc),
        a6 = __shfl(v1.z, Lc), a7 = __shfl(v1.w, Lc);
  // uniform scalar selection among the 8 (static indexing only)
  int k = -1; float res = 0.f, bsb = 0.f, c = exL;
#define PICK(j, aj) { float cn = c + (aj); if (k < 0 && cn >= target) { k = j; res = target - c; bsb = (aj); } c = cn; }
  PICK(0, a0) PICK(1, a1) PICK(2, a2) PICK(3, a3)
  PICK(4, a4) PICK(5, a5) PICK(6, a6) PICK(7, a7)
#undef PICK
#define LASTP(j, aj) { if (k < 0 && (aj) > 0.f) { k = j; res = (aj); bsb = (aj); } }
  LASTP(7, a7) LASTP(6, a6) LASTP(5, a5) LASTP(4, a4)
  LASTP(3, a3) LASTP(2, a2) LASTP(1, a1) LASTP(0, a0)
#undef LASTP
  if (k < 0) {  // pathological: chosen lane empty -> uniform fallback
    if (lane == 0) nidx[draw] = mix32((unsigned)draw * 0x68bc21ebu + 77u) & (NN - 1);
    return;
  }
  const int blk = Lc * 8 + k;
  const int cb  = blk * 16;

  // ---- stage 2: recompute the 16 weights in fp32 (4 lanes/col x 32 dims)
  // xbf chunks: col side = blk*256 + part*64 + vv*16 + c_local;
  //             row side = (row>>4)*256 + part*64 + vv*16 + (row&15).
  const int c_local = lane >> 2;
  const int part    = lane & 3;
  const int col     = cb + c_local;
  float dot = 0.f;
#pragma unroll
  for (int vv = 0; vv < 4; ++vv) {
    bf16x8 cv = *reinterpret_cast<const bf16x8*>(
        xbf + ((size_t)blk * 256 + part * 64 + vv * 16 + c_local) * 8);
    bf16x8 av = *reinterpret_cast<const bf16x8*>(
        xbf + ((size_t)(row >> 4) * 256 + part * 64 + vv * 16 + (row & 15)) * 8);
#pragma unroll
    for (int j = 0; j < 8; ++j) {
      float cf = __uint_as_float(((unsigned)(unsigned short)cv[j]) << 16);
      float af = __uint_as_float(((unsigned)(unsigned short)av[j]) << 16);
      dot = fmaf(cf, af, dot);
    }
  }
  dot += __shfl_xor(dot, 1);
  dot += __shfl_xor(dot, 2);
  float w = wfun(dot, col, row >> 3);
  float v = (part == 0) ? w : 0.f;
  float pre2 = wave_incl_scan(v, lane);
  float SW = __shfl(pre2, 63);
  unsigned result;
  if (SW > 0.f) {
    float t2 = (res / bsb) * SW;                 // renormalized residual
    unsigned long long m = __ballot((v > 0.f) && (pre2 >= t2));
    if (m) result = (unsigned)(cb + (((int)__ffsll(m) - 1) >> 2));
    else {
      unsigned long long m2 = __ballot(v > 0.f); // rounding overrun -> clamp
      result = (unsigned)(cb + ((63 - (int)__clzll(m2)) >> 2));
    }
  } else {
    result = mix32((unsigned)draw * 0x68bc21ebu + 77u) & (NN - 1);
  }
  if (lane == 0) nidx[draw] = result;
}

// All five output chunks, float4-vectorized, nontemporal stores (R17 version).
__global__ __launch_bounds__(256) void write_outputs(const float* __restrict__ x,
                                                     const unsigned* __restrict__ nidx,
                                                     float* __restrict__ out) {
  const int qq = blockIdx.x * 256 + threadIdx.x;
  if (qq >= TOTAL / 4) return;
  const int e = qq * 4;
  float4 v;
  if (e < O0_END) {
    v.x = (float)((e    ) / KM1);
    v.y = (float)((e + 1) / KM1);
    v.z = (float)((e + 2) / KM1);
    v.w = (float)((e + 3) / KM1);                        // a_idx
  } else if (e < O1_END) {
    int t = e - O0_END; int sidx = t >> 7; int d = t & 127;
    v = *reinterpret_cast<const float4*>(x + (size_t)(sidx / KM1) * DD + d);   // x[a_idx]
  } else if (e < O2_END) {
    int t = e - O1_END; int sidx = t >> 7; int d = t & 127;
    int i = sidx / KM1; int j = sidx - i * KM1; int m = i & 7;
    int p = (i >> 3) * 8 + j + (j >= m ? 1 : 0);         // block members, skip self
    v = *reinterpret_cast<const float4*>(x + (size_t)p * DD + d);              // x[p_idx]
  } else if (e < O3_END) {
    int t = e - O2_END; int sidx = t >> 7; int d = t & 127;
    int nix = (int)nidx[sidx];
    v = *reinterpret_cast<const float4*>(x + (size_t)nix * DD + d);            // x[n_idx]
  } else {
    v = *reinterpret_cast<const float4*>(x + (e - O3_END));                    // x
  }
  f32x4 nv = {v.x, v.y, v.z, v.w};
  __builtin_nontemporal_store(nv, reinterpret_cast<f32x4*>(out + e));
}

extern "C" void kernel_launch(void* const* d_in, const int* in_sizes, int n_in,
                              void* d_out, int out_size, void* d_ws, size_t ws_size,
                              hipStream_t stream) {
  const float* x = (const float*)d_in[0];
  float* out = (float*)d_out;

  float* bs = (float*)d_ws;                                            // 8192*512 f32 = 16MB
  unsigned* nidx = (unsigned*)((char*)d_ws + (size_t)NN * NBLK * 4);   // 57344 u32
  unsigned short* xbf = (unsigned short*)((char*)nidx + NKEY * 4);     // 2MB bf16 swizzled

  hipLaunchKernelGGL(to_bf16, dim3(NN * DD / 8 / 256), dim3(256), 0, stream, x, xbf);
  hipLaunchKernelGGL(pass_a, dim3(1024), dim3(TPB), 0, stream, xbf, bs);
  hipLaunchKernelGGL(pass_b, dim3(NKEY / 4), dim3(TPB), 0, stream, xbf, bs, nidx);
  hipLaunchKernelGGL(write_outputs, dim3(TOTAL / 4 / 256), dim3(256), 0, stream,
                     x, nidx, out);
}

// Round 23
// 105.617 us; speedup vs baseline: 1.3114x; 1.2068x over previous
//
#include <hip/hip_runtime.h>

#define NN   8192
#define DD   128
#define KM1  7
#define TPB  256
#define NBLK 512      // 16-col weight blocks per row

#define O0_END   57344
#define O1_END   7397376
#define O2_END   14737408
#define O3_END   22077440
#define TOTAL    23126016
#define NKEY     57344

typedef __attribute__((ext_vector_type(8))) short bf16x8;
typedef __attribute__((ext_vector_type(4))) float f32x4;

__device__ __forceinline__ unsigned mix32(unsigned h) {
  h ^= h >> 16; h *= 0x85ebca6bu; h ^= h >> 13; h *= 0xc2b2ae35u; h ^= h >> 16;
  return h;
}

// Weight of pair given dot (bf16 inputs). Same formula in both passes.
__device__ __forceinline__ float wfun(float dot, int col, int rowblk) {
  float d2m = fmaxf(fmaf(-2.f, dot, 2.f), 0.25f);      // clamped dist^2
  bool vb = ((col >> 3) != rowblk) && (d2m < 1.96f);   // block mask + dist<1.4
  float lgd = __log2f(d2m);
  float om  = fmaf(-0.25f, d2m, 1.f);
  float lgo = __log2f(om);
  float lgw = fmaf(-62.5f, lgo, fmaf(-63.f, lgd, -63.f));  // log2 w
  float w   = __builtin_amdgcn_exp2f(lgw);             // w in [8e-20, 5e20]
  return vb ? w : 0.f;
}

__device__ __forceinline__ float wave_incl_scan(float v, int lane) {
#pragma unroll
  for (int off = 1; off < 64; off <<= 1) {
    float t = __shfl_up(v, off);
    if (lane >= off) v += t;
  }
  return v;
}

// fp32 -> bf16 (RNE) into BOTH layouts:
//  xb  : row-major [8192][128]            (pass_b stage-2 reads)
//  xbf : fragment-swizzled, chunk c = R*256 + kk*64 + g*16 + l15 holds
//        x[16R+l15][kk*32+g*8 .. +8)      (pass_a coalesced fragment loads)
__global__ __launch_bounds__(256) void to_bf16(const float* __restrict__ x,
                                               unsigned short* __restrict__ xb,
                                               unsigned short* __restrict__ xbf) {
  const int c = blockIdx.x * 256 + threadIdx.x;   // 131072 chunks
  const int l15 = c & 15, g = (c >> 4) & 3, kk = (c >> 6) & 3, R = c >> 8;
  const int row = R * 16 + l15;
  const int j0  = kk * 32 + g * 8;
  const float* src = x + (size_t)row * DD + j0;
  float4 a = *reinterpret_cast<const float4*>(src);
  float4 b = *reinterpret_cast<const float4*>(src + 4);
  unsigned short o[8];
  unsigned u;
  u = __float_as_uint(a.x); o[0] = (unsigned short)((u + 0x7FFFu + ((u >> 16) & 1u)) >> 16);
  u = __float_as_uint(a.y); o[1] = (unsigned short)((u + 0x7FFFu + ((u >> 16) & 1u)) >> 16);
  u = __float_as_uint(a.z); o[2] = (unsigned short)((u + 0x7FFFu + ((u >> 16) & 1u)) >> 16);
  u = __float_as_uint(a.w); o[3] = (unsigned short)((u + 0x7FFFu + ((u >> 16) & 1u)) >> 16);
  u = __float_as_uint(b.x); o[4] = (unsigned short)((u + 0x7FFFu + ((u >> 16) & 1u)) >> 16);
  u = __float_as_uint(b.y); o[5] = (unsigned short)((u + 0x7FFFu + ((u >> 16) & 1u)) >> 16);
  u = __float_as_uint(b.z); o[6] = (unsigned short)((u + 0x7FFFu + ((u >> 16) & 1u)) >> 16);
  u = __float_as_uint(b.w); o[7] = (unsigned short)((u + 0x7FFFu + ((u >> 16) & 1u)) >> 16);
  bf16x8 pk;
#pragma unroll
  for (int j = 0; j < 8; ++j) pk[j] = (short)o[j];
  *reinterpret_cast<bf16x8*>(xbf + (size_t)c * 8) = pk;
  *reinterpret_cast<bf16x8*>(xb + (size_t)row * DD + j0) = pk;
}

// Pass A (swapped operands, 64 rows/wave): wave = 64 rows x 256 cols (8 tiles),
// grid = 32 row-groups x 32 col-chunks = 1024 blocks. All fragment loads from
// xbf are lane-consecutive -> fully coalesced (1 KB per wave-load).
__global__ __launch_bounds__(TPB, 2) void pass_a(const unsigned short* __restrict__ xbf,
                                                 float* __restrict__ bs) {
  const int tid  = threadIdx.x;
  const int lane = tid & 63;
  const int wid  = tid >> 6;
  const int l15  = lane & 15;
  const int g    = lane >> 4;
  const int i0   = ((int)(blockIdx.x >> 5)) * 256 + wid * 64;  // wave's 64 rows
  const int oc   = (int)(blockIdx.x & 31);
  const int c0   = oc * 256;

  // row fragments: group (i0>>4)+rg, chunk base + kk*512 + lane*8 elements
  bf16x8 rw[4][4];
#pragma unroll
  for (int rg = 0; rg < 4; ++rg) {
    const unsigned short* rp = xbf + ((size_t)(i0 >> 4) + rg) * 2048 + lane * 8;
#pragma unroll
    for (int kk = 0; kk < 4; ++kk)
      rw[rg][kk] = *reinterpret_cast<const bf16x8*>(rp + kk * 512);
  }

  float bsl[16];     // this lane's row (i0+lane): 16 block sums, static-indexed
#pragma unroll
  for (int j = 0; j < 16; ++j) bsl[j] = 0.f;

#pragma unroll 1
  for (int t = 0; t < 8; ++t) {           // 32-col tiles = 2 x 16-col blocks
    const int ct = c0 + t * 32;
    bf16x8 cf[2][4];
#pragma unroll
    for (int mf = 0; mf < 2; ++mf) {
      const unsigned short* cp = xbf + ((size_t)(ct >> 4) + mf) * 2048 + lane * 8;
#pragma unroll
      for (int kk = 0; kk < 4; ++kk)
        cf[mf][kk] = *reinterpret_cast<const bf16x8*>(cp + kk * 512);
    }

    f32x4 acc[2][4];
#pragma unroll
    for (int mf = 0; mf < 2; ++mf)
#pragma unroll
      for (int rg = 0; rg < 4; ++rg) acc[mf][rg] = (f32x4){0.f, 0.f, 0.f, 0.f};

#pragma unroll
    for (int mf = 0; mf < 2; ++mf)
#pragma unroll
      for (int rg = 0; rg < 4; ++rg)
#pragma unroll
        for (int kk = 0; kk < 4; ++kk)
          acc[mf][rg] = __builtin_amdgcn_mfma_f32_16x16x32_bf16(cf[mf][kk], rw[rg][kk],
                                                                acc[mf][rg], 0, 0, 0);

    // D layout [m89]: n = l15 -> ROW (group rg); m = g*4+reg -> COL
#pragma unroll
    for (int mf = 0; mf < 2; ++mf) {
      float s[4];
#pragma unroll
      for (int rg = 0; rg < 4; ++rg) {
        const int rowblk = (i0 + rg * 16 + l15) >> 3;
        float sv = 0.f;
#pragma unroll
        for (int r = 0; r < 4; ++r) {
          const int col = ct + mf * 16 + g * 4 + r;
          sv += wfun(acc[mf][rg][r], col, rowblk);
        }
        sv += __shfl_xor(sv, 16);
        sv += __shfl_xor(sv, 32);          // sum over g -> 16-col block sum
        s[rg] = sv;
      }
      // keep the rg == g slice: lane now owns row i0+lane
      float v = (g == 0) ? s[0] : (g == 1) ? s[1] : (g == 2) ? s[2] : s[3];
      bsl[2 * t + mf] = v;
    }
  }

  // coalesced write: lane's row chunk = 16 consecutive floats (one 64 B line)
  float* dst = bs + (size_t)(i0 + lane) * NBLK + oc * 16;
#pragma unroll
  for (int k4 = 0; k4 < 4; ++k4) {
    f32x4 o = {bsl[4 * k4], bsl[4 * k4 + 1], bsl[4 * k4 + 2], bsl[4 * k4 + 3]};
    *reinterpret_cast<f32x4*>(dst + 4 * k4) = o;
  }
}

// Pass B (R17-proven version, row-major xb reads): one wave per draw.
// Two-level inverse-CDF: 512 block sums -> 16-col block -> fp32 recompute.
__global__ __launch_bounds__(TPB) void pass_b(const unsigned short* __restrict__ xb,
                                              const float* __restrict__ bs,
                                              unsigned* __restrict__ nidx) {
  const int lane = threadIdx.x & 63;
  const int wid  = threadIdx.x >> 6;
  const int draw = (int)blockIdx.x * 4 + wid;   // 57344 draws
  const int row  = draw / KM1;

  // ---- stage 1: scan the row's 512 block sums (8 per lane)
  const float* bsr = bs + (size_t)row * NBLK;
  float4 v0 = *reinterpret_cast<const float4*>(bsr + lane * 8);
  float4 v1 = *reinterpret_cast<const float4*>(bsr + lane * 8 + 4);
  float s8 = ((v0.x + v0.y) + (v0.z + v0.w)) + ((v1.x + v1.y) + (v1.z + v1.w));
  float pre = wave_incl_scan(s8, lane);
  float W = __shfl(pre, 63);

  unsigned h = mix32((unsigned)draw * 2654435761u + 0x12345u);
  float u = ((float)(h >> 9) + 0.5f) * (1.0f / 8388608.0f);   // (0,1)

  if (!(W > 0.f)) {  // degenerate row -> uniform over all n
    if (lane == 0) nidx[draw] = mix32((unsigned)draw * 0x68bc21ebu + 77u) & (NN - 1);
    return;
  }
  float target = u * W;

  unsigned long long ball = __ballot(pre >= target);
  int Lc = ball ? ((int)__ffsll(ball) - 1) : 63;
  float exL = __shfl(pre - s8, Lc);
  float a0 = __shfl(v0.x, Lc), a1 = __shfl(v0.y, Lc), a2 = __shfl(v0.z, Lc),
        a3 = __shfl(v0.w, Lc), a4 = __shfl(v1.x, Lc), a5 = __shfl(v1.y, Lc),
        a6 = __shfl(v1.z, Lc), a7 = __shfl(v1.w, Lc);
  // uniform scalar selection among the 8 (static indexing only)
  int k = -1; float res = 0.f, bsb = 0.f, c = exL;
#define PICK(j, aj) { float cn = c + (aj); if (k < 0 && cn >= target) { k = j; res = target - c; bsb = (aj); } c = cn; }
  PICK(0, a0) PICK(1, a1) PICK(2, a2) PICK(3, a3)
  PICK(4, a4) PICK(5, a5) PICK(6, a6) PICK(7, a7)
#undef PICK
#define LASTP(j, aj) { if (k < 0 && (aj) > 0.f) { k = j; res = (aj); bsb = (aj); } }
  LASTP(7, a7) LASTP(6, a6) LASTP(5, a5) LASTP(4, a4)
  LASTP(3, a3) LASTP(2, a2) LASTP(1, a1) LASTP(0, a0)
#undef LASTP
  if (k < 0) {  // pathological: chosen lane empty -> uniform fallback
    if (lane == 0) nidx[draw] = mix32((unsigned)draw * 0x68bc21ebu + 77u) & (NN - 1);
    return;
  }
  const int blk = Lc * 8 + k;
  const int cb  = blk * 16;

  // ---- stage 2: recompute the 16 weights in fp32 (4 lanes/col x 32 dims)
  const int c_local = lane >> 2;
  const int part    = lane & 3;
  const int col     = cb + c_local;
  const unsigned short* cp = xb + (size_t)col * DD + part * 32;
  const unsigned short* ap = xb + (size_t)row * DD + part * 32;
  float dot = 0.f;
#pragma unroll
  for (int vv = 0; vv < 4; ++vv) {
    bf16x8 cv = *reinterpret_cast<const bf16x8*>(cp + vv * 8);
    bf16x8 av = *reinterpret_cast<const bf16x8*>(ap + vv * 8);
#pragma unroll
    for (int j = 0; j < 8; ++j) {
      float cf = __uint_as_float(((unsigned)(unsigned short)cv[j]) << 16);
      float af = __uint_as_float(((unsigned)(unsigned short)av[j]) << 16);
      dot = fmaf(cf, af, dot);
    }
  }
  dot += __shfl_xor(dot, 1);
  dot += __shfl_xor(dot, 2);
  float w = wfun(dot, col, row >> 3);
  float v = (part == 0) ? w : 0.f;
  float pre2 = wave_incl_scan(v, lane);
  float SW = __shfl(pre2, 63);
  unsigned result;
  if (SW > 0.f) {
    float t2 = (res / bsb) * SW;                 // renormalized residual
    unsigned long long m = __ballot((v > 0.f) && (pre2 >= t2));
    if (m) result = (unsigned)(cb + (((int)__ffsll(m) - 1) >> 2));
    else {
      unsigned long long m2 = __ballot(v > 0.f); // rounding overrun -> clamp
      result = (unsigned)(cb + ((63 - (int)__clzll(m2)) >> 2));
    }
  } else {
    result = mix32((unsigned)draw * 0x68bc21ebu + 77u) & (NN - 1);
  }
  if (lane == 0) nidx[draw] = result;
}

// All five output chunks, float4-vectorized, nontemporal stores (R17 version).
__global__ __launch_bounds__(256) void write_outputs(const float* __restrict__ x,
                                                     const unsigned* __restrict__ nidx,
                                                     float* __restrict__ out) {
  const int qq = blockIdx.x * 256 + threadIdx.x;
  if (qq >= TOTAL / 4) return;
  const int e = qq * 4;
  float4 v;
  if (e < O0_END) {
    v.x = (float)((e    ) / KM1);
    v.y = (float)((e + 1) / KM1);
    v.z = (float)((e + 2) / KM1);
    v.w = (float)((e + 3) / KM1);                        // a_idx
  } else if (e < O1_END) {
    int t = e - O0_END; int sidx = t >> 7; int d = t & 127;
    v = *reinterpret_cast<const float4*>(x + (size_t)(sidx / KM1) * DD + d);   // x[a_idx]
  } else if (e < O2_END) {
    int t = e - O1_END; int sidx = t >> 7; int d = t & 127;
    int i = sidx / KM1; int j = sidx - i * KM1; int m = i & 7;
    int p = (i >> 3) * 8 + j + (j >= m ? 1 : 0);         // block members, skip self
    v = *reinterpret_cast<const float4*>(x + (size_t)p * DD + d);              // x[p_idx]
  } else if (e < O3_END) {
    int t = e - O2_END; int sidx = t >> 7; int d = t & 127;
    int nix = (int)nidx[sidx];
    v = *reinterpret_cast<const float4*>(x + (size_t)nix * DD + d);            // x[n_idx]
  } else {
    v = *reinterpret_cast<const float4*>(x + (e - O3_END));                    // x
  }
  f32x4 nv = {v.x, v.y, v.z, v.w};
  __builtin_nontemporal_store(nv, reinterpret_cast<f32x4*>(out + e));
}

extern "C" void kernel_launch(void* const* d_in, const int* in_sizes, int n_in,
                              void* d_out, int out_size, void* d_ws, size_t ws_size,
                              hipStream_t stream) {
  const float* x = (const float*)d_in[0];
  float* out = (float*)d_out;

  float* bs = (float*)d_ws;                                            // 16 MB
  unsigned* nidx = (unsigned*)((char*)d_ws + (size_t)NN * NBLK * 4);   // 229 KB
  unsigned short* xb  = (unsigned short*)((char*)nidx + NKEY * 4);     // 2 MB row-major
  unsigned short* xbf = (unsigned short*)((char*)xb + (size_t)NN * DD * 2);  // 2 MB swizzled

  hipLaunchKernelGGL(to_bf16, dim3(NN * DD / 8 / 256), dim3(256), 0, stream, x, xb, xbf);
  hipLaunchKernelGGL(pass_a, dim3(1024), dim3(TPB), 0, stream, xbf, bs);
  hipLaunchKernelGGL(pass_b, dim3(NKEY / 4), dim3(TPB), 0, stream, xb, bs, nidx);
  hipLaunchKernelGGL(write_outputs, dim3(TOTAL / 4 / 256), dim3(256), 0, stream,
                     x, nidx, out);
}

// Round 24
// 103.430 us; speedup vs baseline: 1.3391x; 1.0211x over previous
//
#include <hip/hip_runtime.h>

#define NN   8192
#define DD   128
#define KM1  7
#define TPB  256
#define NBLK 512      // 16-col weight blocks per row

#define O0_END   57344
#define O1_END   7397376
#define O2_END   14737408
#define O3_END   22077440
#define TOTAL    23126016
#define NKEY     57344

typedef __attribute__((ext_vector_type(8))) short bf16x8;
typedef __attribute__((ext_vector_type(4))) float f32x4;

__device__ __forceinline__ unsigned mix32(unsigned h) {
  h ^= h >> 16; h *= 0x85ebca6bu; h ^= h >> 13; h *= 0xc2b2ae35u; h ^= h >> 16;
  return h;
}

// Weight of pair given dot (bf16 inputs). Same formula in both passes.
__device__ __forceinline__ float wfun(float dot, int col, int rowblk) {
  float d2m = fmaxf(fmaf(-2.f, dot, 2.f), 0.25f);      // clamped dist^2
  bool vb = ((col >> 3) != rowblk) && (d2m < 1.96f);   // block mask + dist<1.4
  float lgd = __log2f(d2m);
  float om  = fmaf(-0.25f, d2m, 1.f);
  float lgo = __log2f(om);
  float lgw = fmaf(-62.5f, lgo, fmaf(-63.f, lgd, -63.f));  // log2 w
  float w   = __builtin_amdgcn_exp2f(lgw);             // w in [8e-20, 5e20]
  return vb ? w : 0.f;
}

__device__ __forceinline__ float wave_incl_scan(float v, int lane) {
#pragma unroll
  for (int off = 1; off < 64; off <<= 1) {
    float t = __shfl_up(v, off);
    if (lane >= off) v += t;
  }
  return v;
}

// fp32 -> bf16 (RNE) into BOTH layouts:
//  xb  : row-major [8192][128]            (pass_b stage-2 reads)
//  xbf : fragment-swizzled, chunk c = R*256 + kk*64 + g*16 + l15 holds
//        x[16R+l15][kk*32+g*8 .. +8)      (pass_a coalesced fragment loads)
__global__ __launch_bounds__(256) void to_bf16(const float* __restrict__ x,
                                               unsigned short* __restrict__ xb,
                                               unsigned short* __restrict__ xbf) {
  const int c = blockIdx.x * 256 + threadIdx.x;   // 131072 chunks
  const int l15 = c & 15, g = (c >> 4) & 3, kk = (c >> 6) & 3, R = c >> 8;
  const int row = R * 16 + l15;
  const int j0  = kk * 32 + g * 8;
  const float* src = x + (size_t)row * DD + j0;
  float4 a = *reinterpret_cast<const float4*>(src);
  float4 b = *reinterpret_cast<const float4*>(src + 4);
  unsigned short o[8];
  unsigned u;
  u = __float_as_uint(a.x); o[0] = (unsigned short)((u + 0x7FFFu + ((u >> 16) & 1u)) >> 16);
  u = __float_as_uint(a.y); o[1] = (unsigned short)((u + 0x7FFFu + ((u >> 16) & 1u)) >> 16);
  u = __float_as_uint(a.z); o[2] = (unsigned short)((u + 0x7FFFu + ((u >> 16) & 1u)) >> 16);
  u = __float_as_uint(a.w); o[3] = (unsigned short)((u + 0x7FFFu + ((u >> 16) & 1u)) >> 16);
  u = __float_as_uint(b.x); o[4] = (unsigned short)((u + 0x7FFFu + ((u >> 16) & 1u)) >> 16);
  u = __float_as_uint(b.y); o[5] = (unsigned short)((u + 0x7FFFu + ((u >> 16) & 1u)) >> 16);
  u = __float_as_uint(b.z); o[6] = (unsigned short)((u + 0x7FFFu + ((u >> 16) & 1u)) >> 16);
  u = __float_as_uint(b.w); o[7] = (unsigned short)((u + 0x7FFFu + ((u >> 16) & 1u)) >> 16);
  bf16x8 pk;
#pragma unroll
  for (int j = 0; j < 8; ++j) pk[j] = (short)o[j];
  *reinterpret_cast<bf16x8*>(xbf + (size_t)c * 8) = pk;
  *reinterpret_cast<bf16x8*>(xb + (size_t)row * DD + j0) = pk;
}

// Pass A (swapped operands, 64 rows/wave): wave = 64 rows x 256 cols (8 tiles),
// grid = 32 row-groups x 32 col-chunks = 1024 blocks. All fragment loads from
// xbf are lane-consecutive -> fully coalesced (1 KB per wave-load).
__global__ __launch_bounds__(TPB, 2) void pass_a(const unsigned short* __restrict__ xbf,
                                                 float* __restrict__ bs) {
  const int tid  = threadIdx.x;
  const int lane = tid & 63;
  const int wid  = tid >> 6;
  const int l15  = lane & 15;
  const int g    = lane >> 4;
  const int i0   = ((int)(blockIdx.x >> 5)) * 256 + wid * 64;  // wave's 64 rows
  const int oc   = (int)(blockIdx.x & 31);
  const int c0   = oc * 256;

  // row fragments: group (i0>>4)+rg, chunk base + kk*512 + lane*8 elements
  bf16x8 rw[4][4];
#pragma unroll
  for (int rg = 0; rg < 4; ++rg) {
    const unsigned short* rp = xbf + ((size_t)(i0 >> 4) + rg) * 2048 + lane * 8;
#pragma unroll
    for (int kk = 0; kk < 4; ++kk)
      rw[rg][kk] = *reinterpret_cast<const bf16x8*>(rp + kk * 512);
  }

  float bsl[16];     // this lane's row (i0+lane): 16 block sums, static-indexed
#pragma unroll
  for (int j = 0; j < 16; ++j) bsl[j] = 0.f;

#pragma unroll 1
  for (int t = 0; t < 8; ++t) {           // 32-col tiles = 2 x 16-col blocks
    const int ct = c0 + t * 32;
    bf16x8 cf[2][4];
#pragma unroll
    for (int mf = 0; mf < 2; ++mf) {
      const unsigned short* cp = xbf + ((size_t)(ct >> 4) + mf) * 2048 + lane * 8;
#pragma unroll
      for (int kk = 0; kk < 4; ++kk)
        cf[mf][kk] = *reinterpret_cast<const bf16x8*>(cp + kk * 512);
    }

    f32x4 acc[2][4];
#pragma unroll
    for (int mf = 0; mf < 2; ++mf)
#pragma unroll
      for (int rg = 0; rg < 4; ++rg) acc[mf][rg] = (f32x4){0.f, 0.f, 0.f, 0.f};

#pragma unroll
    for (int mf = 0; mf < 2; ++mf)
#pragma unroll
      for (int rg = 0; rg < 4; ++rg)
#pragma unroll
        for (int kk = 0; kk < 4; ++kk)
          acc[mf][rg] = __builtin_amdgcn_mfma_f32_16x16x32_bf16(cf[mf][kk], rw[rg][kk],
                                                                acc[mf][rg], 0, 0, 0);

    // D layout [m89]: n = l15 -> ROW (group rg); m = g*4+reg -> COL
#pragma unroll
    for (int mf = 0; mf < 2; ++mf) {
      float s[4];
#pragma unroll
      for (int rg = 0; rg < 4; ++rg) {
        const int rowblk = (i0 + rg * 16 + l15) >> 3;
        float sv = 0.f;
#pragma unroll
        for (int r = 0; r < 4; ++r) {
          const int col = ct + mf * 16 + g * 4 + r;
          sv += wfun(acc[mf][rg][r], col, rowblk);
        }
        sv += __shfl_xor(sv, 16);
        sv += __shfl_xor(sv, 32);          // sum over g -> 16-col block sum
        s[rg] = sv;
      }
      // keep the rg == g slice: lane now owns row i0+lane
      float v = (g == 0) ? s[0] : (g == 1) ? s[1] : (g == 2) ? s[2] : s[3];
      bsl[2 * t + mf] = v;
    }
  }

  // coalesced write: lane's row chunk = 16 consecutive floats (one 64 B line)
  float* dst = bs + (size_t)(i0 + lane) * NBLK + oc * 16;
#pragma unroll
  for (int k4 = 0; k4 < 4; ++k4) {
    f32x4 o = {bsl[4 * k4], bsl[4 * k4 + 1], bsl[4 * k4 + 2], bsl[4 * k4 + 3]};
    *reinterpret_cast<f32x4*>(dst + 4 * k4) = o;
  }
}

// Pass B: ONE WAVE PER ROW (7 draws share stage-1 scan + row-side operand).
// Per draw: RNG, block-select over the shared prefix, 16-col fp32 recompute.
__global__ __launch_bounds__(TPB) void pass_b(const unsigned short* __restrict__ xb,
                                              const float* __restrict__ bs,
                                              unsigned* __restrict__ nidx) {
  const int lane = threadIdx.x & 63;
  const int wid  = threadIdx.x >> 6;
  const int row  = (int)blockIdx.x * 4 + wid;   // 8192 rows

  // ---- stage 1 (once per row): scan the row's 512 block sums (8 per lane)
  const float* bsr = bs + (size_t)row * NBLK;
  float4 v0 = *reinterpret_cast<const float4*>(bsr + lane * 8);
  float4 v1 = *reinterpret_cast<const float4*>(bsr + lane * 8 + 4);
  float s8 = ((v0.x + v0.y) + (v0.z + v0.w)) + ((v1.x + v1.y) + (v1.z + v1.w));
  float pre = wave_incl_scan(s8, lane);
  float W = __shfl(pre, 63);
  float ex = pre - s8;                          // exclusive prefix

  // hoist row-side stage-2 operand (same for all 7 draws)
  const int c_local = lane >> 2;
  const int part    = lane & 3;
  const unsigned short* ap = xb + (size_t)row * DD + part * 32;
  bf16x8 av0 = *reinterpret_cast<const bf16x8*>(ap);
  bf16x8 av1 = *reinterpret_cast<const bf16x8*>(ap + 8);
  bf16x8 av2 = *reinterpret_cast<const bf16x8*>(ap + 16);
  bf16x8 av3 = *reinterpret_cast<const bf16x8*>(ap + 24);
  const int rowblk = row >> 3;

#pragma unroll 1
  for (int s = 0; s < KM1; ++s) {
    const int draw = row * KM1 + s;
    unsigned result;
    unsigned h = mix32((unsigned)draw * 2654435761u + 0x12345u);
    float u = ((float)(h >> 9) + 0.5f) * (1.0f / 8388608.0f);   // (0,1)

    if (!(W > 0.f)) {   // degenerate row -> uniform over all n
      result = mix32((unsigned)draw * 0x68bc21ebu + 77u) & (NN - 1);
      if (lane == 0) nidx[draw] = result;
      continue;
    }
    float target = u * W;

    unsigned long long ball = __ballot(pre >= target);
    int Lc = ball ? ((int)__ffsll(ball) - 1) : 63;
    float exL = __shfl(ex, Lc);
    float a0 = __shfl(v0.x, Lc), a1 = __shfl(v0.y, Lc), a2 = __shfl(v0.z, Lc),
          a3 = __shfl(v0.w, Lc), a4 = __shfl(v1.x, Lc), a5 = __shfl(v1.y, Lc),
          a6 = __shfl(v1.z, Lc), a7 = __shfl(v1.w, Lc);
    int k = -1; float res = 0.f, bsb = 0.f, c = exL;
#define PICK(j, aj) { float cn = c + (aj); if (k < 0 && cn >= target) { k = j; res = target - c; bsb = (aj); } c = cn; }
    PICK(0, a0) PICK(1, a1) PICK(2, a2) PICK(3, a3)
    PICK(4, a4) PICK(5, a5) PICK(6, a6) PICK(7, a7)
#undef PICK
#define LASTP(j, aj) { if (k < 0 && (aj) > 0.f) { k = j; res = (aj); bsb = (aj); } }
    LASTP(7, a7) LASTP(6, a6) LASTP(5, a5) LASTP(4, a4)
    LASTP(3, a3) LASTP(2, a2) LASTP(1, a1) LASTP(0, a0)
#undef LASTP
    if (k < 0) {   // pathological: chosen lane empty -> uniform fallback
      result = mix32((unsigned)draw * 0x68bc21ebu + 77u) & (NN - 1);
      if (lane == 0) nidx[draw] = result;
      continue;
    }
    const int blk = Lc * 8 + k;
    const int cb  = blk * 16;

    // ---- stage 2: recompute the 16 weights in fp32 (4 lanes/col x 32 dims)
    const int col = cb + c_local;
    const unsigned short* cp = xb + (size_t)col * DD + part * 32;
    float dot = 0.f;
    {
      bf16x8 cv = *reinterpret_cast<const bf16x8*>(cp);
#pragma unroll
      for (int j = 0; j < 8; ++j)
        dot = fmaf(__uint_as_float(((unsigned)(unsigned short)cv[j]) << 16),
                   __uint_as_float(((unsigned)(unsigned short)av0[j]) << 16), dot);
      cv = *reinterpret_cast<const bf16x8*>(cp + 8);
#pragma unroll
      for (int j = 0; j < 8; ++j)
        dot = fmaf(__uint_as_float(((unsigned)(unsigned short)cv[j]) << 16),
                   __uint_as_float(((unsigned)(unsigned short)av1[j]) << 16), dot);
      cv = *reinterpret_cast<const bf16x8*>(cp + 16);
#pragma unroll
      for (int j = 0; j < 8; ++j)
        dot = fmaf(__uint_as_float(((unsigned)(unsigned short)cv[j]) << 16),
                   __uint_as_float(((unsigned)(unsigned short)av2[j]) << 16), dot);
      cv = *reinterpret_cast<const bf16x8*>(cp + 24);
#pragma unroll
      for (int j = 0; j < 8; ++j)
        dot = fmaf(__uint_as_float(((unsigned)(unsigned short)cv[j]) << 16),
                   __uint_as_float(((unsigned)(unsigned short)av3[j]) << 16), dot);
    }
    dot += __shfl_xor(dot, 1);
    dot += __shfl_xor(dot, 2);
    float w = wfun(dot, col, rowblk);
    float v = (part == 0) ? w : 0.f;
    float pre2 = wave_incl_scan(v, lane);
    float SW = __shfl(pre2, 63);
    if (SW > 0.f) {
      float t2 = (res / bsb) * SW;                 // renormalized residual
      unsigned long long m = __ballot((v > 0.f) && (pre2 >= t2));
      if (m) result = (unsigned)(cb + (((int)__ffsll(m) - 1) >> 2));
      else {
        unsigned long long m2 = __ballot(v > 0.f); // rounding overrun -> clamp
        result = (unsigned)(cb + ((63 - (int)__clzll(m2)) >> 2));
      }
    } else {
      result = mix32((unsigned)draw * 0x68bc21ebu + 77u) & (NN - 1);
    }
    if (lane == 0) nidx[draw] = result;
  }
}

// All five output chunks, float4-vectorized, nontemporal stores (R17 version).
__global__ __launch_bounds__(256) void write_outputs(const float* __restrict__ x,
                                                     const unsigned* __restrict__ nidx,
                                                     float* __restrict__ out) {
  const int qq = blockIdx.x * 256 + threadIdx.x;
  if (qq >= TOTAL / 4) return;
  const int e = qq * 4;
  float4 v;
  if (e < O0_END) {
    v.x = (float)((e    ) / KM1);
    v.y = (float)((e + 1) / KM1);
    v.z = (float)((e + 2) / KM1);
    v.w = (float)((e + 3) / KM1);                        // a_idx
  } else if (e < O1_END) {
    int t = e - O0_END; int sidx = t >> 7; int d = t & 127;
    v = *reinterpret_cast<const float4*>(x + (size_t)(sidx / KM1) * DD + d);   // x[a_idx]
  } else if (e < O2_END) {
    int t = e - O1_END; int sidx = t >> 7; int d = t & 127;
    int i = sidx / KM1; int j = sidx - i * KM1; int m = i & 7;
    int p = (i >> 3) * 8 + j + (j >= m ? 1 : 0);         // block members, skip self
    v = *reinterpret_cast<const float4*>(x + (size_t)p * DD + d);              // x[p_idx]
  } else if (e < O3_END) {
    int t = e - O2_END; int sidx = t >> 7; int d = t & 127;
    int nix = (int)nidx[sidx];
    v = *reinterpret_cast<const float4*>(x + (size_t)nix * DD + d);            // x[n_idx]
  } else {
    v = *reinterpret_cast<const float4*>(x + (e - O3_END));                    // x
  }
  f32x4 nv = {v.x, v.y, v.z, v.w};
  __builtin_nontemporal_store(nv, reinterpret_cast<f32x4*>(out + e));
}

extern "C" void kernel_launch(void* const* d_in, const int* in_sizes, int n_in,
                              void* d_out, int out_size, void* d_ws, size_t ws_size,
                              hipStream_t stream) {
  const float* x = (const float*)d_in[0];
  float* out = (float*)d_out;

  float* bs = (float*)d_ws;                                            // 16 MB
  unsigned* nidx = (unsigned*)((char*)d_ws + (size_t)NN * NBLK * 4);   // 229 KB
  unsigned short* xb  = (unsigned short*)((char*)nidx + NKEY * 4);     // 2 MB row-major
  unsigned short* xbf = (unsigned short*)((char*)xb + (size_t)NN * DD * 2);  // 2 MB swizzled

  hipLaunchKernelGGL(to_bf16, dim3(NN * DD / 8 / 256), dim3(256), 0, stream, x, xb, xbf);
  hipLaunchKernelGGL(pass_a, dim3(1024), dim3(TPB), 0, stream, xbf, bs);
  hipLaunchKernelGGL(pass_b, dim3(NN / 4), dim3(TPB), 0, stream, xb, bs, nidx);
  hipLaunchKernelGGL(write_outputs, dim3(TOTAL / 4 / 256), dim3(256), 0, stream,
                     x, nidx, out);
}